// Round 1
// baseline (9.957 us; speedup 1.0000x reference)
//
#include <hip/hip_runtime.h>

// FizzBuzz counts over i in [0, n) computed in closed form:
//   count of multiples of k in [0,n) = ceil(n/k) = (n + k - 1) / k
//   fizzbuzz = ceil(n/6)
//   buzz     = ceil(n/3) - ceil(n/6)   (i%3==0 but not i%6==0)
//   fizz     = ceil(n/2) - ceil(n/6)   (i%2==0 and i%3!=0; i%3!=0 excludes i%6==0)
// Output order per reference: [fizz, buzz, fizzbuzz], float32, shape (3,1).

__global__ void TorchFizzBuzz_65773129171765_kernel(const int* __restrict__ n_ptr,
                                                    float* __restrict__ out) {
    const int n = n_ptr[0];
    const int m6 = (n + 5) / 6;   // multiples of 6 in [0, n)
    const int m3 = (n + 2) / 3;   // multiples of 3 in [0, n)
    const int m2 = (n + 1) / 2;   // multiples of 2 in [0, n)
    out[0] = (float)(m2 - m6);    // fizz
    out[1] = (float)(m3 - m6);    // buzz
    out[2] = (float)m6;           // fizzbuzz
}

extern "C" void kernel_launch(void* const* d_in, const int* in_sizes, int n_in,
                              void* d_out, int out_size, void* d_ws, size_t ws_size,
                              hipStream_t stream) {
    const int* n_ptr = (const int*)d_in[0];
    float* out = (float*)d_out;
    TorchFizzBuzz_65773129171765_kernel<<<1, 1, 0, stream>>>(n_ptr, out);
}